// Round 4
// baseline (391.263 us; speedup 1.0000x reference)
//
#include <hip/hip_runtime.h>
#include <hip/hip_bf16.h>

#define NN 100000
#define EE 1600000
#define LN_EPS 1e-5f

__device__ __forceinline__ float bf_lo(unsigned u) {
  union { unsigned i; float f; } c; c.i = u << 16; return c.f;
}
__device__ __forceinline__ float bf_hi(unsigned u) {
  union { unsigned i; float f; } c; c.i = u & 0xffff0000u; return c.f;
}
__device__ __forceinline__ float us_bf(unsigned short u) {
  union { unsigned i; float f; } c; c.i = ((unsigned)u) << 16; return c.f;
}
__device__ __forceinline__ unsigned short f2bf(float f) {
  union { float f; unsigned i; } c; c.f = f;
  unsigned b = c.i + 0x7fffu + ((c.i >> 16) & 1u);
  return (unsigned short)(b >> 16);
}
__device__ __forceinline__ float lrelu02(float v) { return v >= 0.f ? v : 0.2f * v; }

// ---------------- K0: detect int64 vs int32 edge_index ----------------
__global__ void k_detect(const void* __restrict__ ei, int* __restrict__ flag) {
  if (threadIdx.x == 0 && blockIdx.x == 0) {
    const unsigned long long* p = (const unsigned long long*)ei;
    int ok = 1;
    for (int i = 0; i < 256; ++i)
      if (p[i] >= (unsigned long long)NN) { ok = 0; break; }
    *flag = ok;  // 1 => int64, 0 => int32
  }
}

// ---------------- K1: normalize edge_index to int32 + dst histogram ----------------
__global__ __launch_bounds__(256) void k_convert_hist(const void* __restrict__ ei,
                                                      const int* __restrict__ flag,
                                                      int* __restrict__ idx32,
                                                      int* __restrict__ counts) {
  int i = blockIdx.x * 256 + threadIdx.x;
  if (i >= 2 * EE) return;
  int v;
  if (*flag) v = (int)((const long long*)ei)[i];
  else       v = ((const int*)ei)[i];
  idx32[i] = v;
  if (i >= EE) atomicAdd(&counts[v], 1);
}

// ---------------- K2: x = P@W (bf16 out), a_src/a_dst (bf16 out) ----------------
__global__ __launch_bounds__(512) void k_gemm_node(
    const float* __restrict__ P, const float* __restrict__ W,
    const float* __restrict__ attS, const float* __restrict__ attD,
    unsigned* __restrict__ xb, unsigned short* __restrict__ a_srcb,
    unsigned short* __restrict__ a_dstb, int nrows) {
  __shared__ float Rl[32 * 66];
  int t = threadIdx.x;
  int w = __builtin_amdgcn_readfirstlane(t >> 6);
  int l = t & 63;
  int rb = blockIdx.x * 64;
  int cb = w * 16;
  float acc[16];
#pragma unroll
  for (int j = 0; j < 16; ++j) acc[j] = 0.f;

  for (int kc = 0; kc < 4; ++kc) {
    __syncthreads();
    {
      int row = t >> 3;
      int k0 = (t & 7) * 4;
      int grow = rb + row;
      float4 v = make_float4(0.f, 0.f, 0.f, 0.f);
      if (grow < nrows)
        v = *(const float4*)(P + (size_t)grow * 128 + kc * 32 + k0);
      Rl[(k0 + 0) * 66 + row] = v.x;
      Rl[(k0 + 1) * 66 + row] = v.y;
      Rl[(k0 + 2) * 66 + row] = v.z;
      Rl[(k0 + 3) * 66 + row] = v.w;
    }
    __syncthreads();
    const float* Wp = W + (size_t)(kc * 32) * 128 + cb;
#pragma unroll 8
    for (int k = 0; k < 32; ++k) {
      float rv = Rl[k * 66 + l];
#pragma unroll
      for (int j = 0; j < 16; ++j) acc[j] = fmaf(rv, Wp[k * 128 + j], acc[j]);
    }
  }
  int row = rb + l;
  if (row < nrows) {
    float sa = 0.f, sd = 0.f;
#pragma unroll
    for (int j = 0; j < 16; ++j) {
      sa = fmaf(acc[j], attS[cb + j], sa);
      sd = fmaf(acc[j], attD[cb + j], sd);
    }
    a_srcb[(size_t)row * 8 + w] = f2bf(sa);
    a_dstb[(size_t)row * 8 + w] = f2bf(sd);
    unsigned pk[8];
#pragma unroll
    for (int m = 0; m < 8; ++m)
      pk[m] = (unsigned)f2bf(acc[2 * m]) | ((unsigned)f2bf(acc[2 * m + 1]) << 16);
    unsigned* xo = xb + (size_t)row * 64 + cb / 2;
    *(uint4*)(xo) = make_uint4(pk[0], pk[1], pk[2], pk[3]);
    *(uint4*)(xo + 4) = make_uint4(pk[4], pk[5], pk[6], pk[7]);
  }
}

// ---------------- K4: per-block sums ----------------
__global__ __launch_bounds__(256) void k_blocksum(const int* __restrict__ counts,
                                                  int* __restrict__ partials, int n) {
  __shared__ int sm[256];
  int t = threadIdx.x;
  int gid = blockIdx.x * 256 + t;
  sm[t] = gid < n ? counts[gid] : 0;
  __syncthreads();
  for (int s = 128; s > 0; s >>= 1) {
    if (t < s) sm[t] += sm[t + s];
    __syncthreads();
  }
  if (t == 0) partials[blockIdx.x] = sm[0];
}

// ---------------- K5: exclusive scan of partials ----------------
__global__ __launch_bounds__(512) void k_scanpartials(int* __restrict__ partials, int nb) {
  __shared__ int sm[512];
  int t = threadIdx.x;
  int v = t < nb ? partials[t] : 0;
  sm[t] = v;
  __syncthreads();
  for (int off = 1; off < 512; off <<= 1) {
    int u = (t >= off) ? sm[t - off] : 0;
    __syncthreads();
    sm[t] += u;
    __syncthreads();
  }
  if (t < nb) partials[t] = sm[t] - v;
}

// ---------------- K6: final exclusive scan -> offsets, cursor ----------------
__global__ __launch_bounds__(256) void k_scanfinal(const int* __restrict__ counts,
                                                   const int* __restrict__ partials,
                                                   int* __restrict__ offsets,
                                                   int* __restrict__ cursor, int n) {
  __shared__ int sm[256];
  int t = threadIdx.x;
  int gid = blockIdx.x * 256 + t;
  int v = gid < n ? counts[gid] : 0;
  sm[t] = v;
  __syncthreads();
  for (int off = 1; off < 256; off <<= 1) {
    int u = (t >= off) ? sm[t - off] : 0;
    __syncthreads();
    sm[t] += u;
    __syncthreads();
  }
  int excl = partials[blockIdx.x] + sm[t] - v;
  if (gid < n) {
    offsets[gid] = excl;
    cursor[gid] = excl;
  }
  if (gid == n - 1) offsets[n] = excl + v;
}

// ---------------- K7: a_edge (bf16, sequential) + CSR index scatter ----------------
__global__ __launch_bounds__(256) void k_edgeprep(
    const float* __restrict__ EA, const float* __restrict__ Wedge,
    const float* __restrict__ attE, const int* __restrict__ src,
    const int* __restrict__ dst, int* __restrict__ cursor,
    int2* __restrict__ pair, unsigned* __restrict__ aedgeb) {
  __shared__ float M[16][8];
  int t = threadIdx.x;
  if (t < 128) {
    int d = t >> 3, h = t & 7;
    float s = 0.f;
#pragma unroll
    for (int c = 0; c < 16; ++c)
      s = fmaf(Wedge[d * 128 + h * 16 + c], attE[h * 16 + c], s);
    M[d][h] = s;
  }
  __syncthreads();
  int e = blockIdx.x * 256 + t;
  if (e >= EE) return;
  float ea[16];
  const float4* ea4 = (const float4*)(EA + (size_t)e * 16);
#pragma unroll
  for (int i = 0; i < 4; ++i) {
    float4 v = ea4[i];
    ea[i * 4] = v.x; ea[i * 4 + 1] = v.y; ea[i * 4 + 2] = v.z; ea[i * 4 + 3] = v.w;
  }
  unsigned pk[4];
#pragma unroll
  for (int m = 0; m < 4; ++m) {
    float s0 = 0.f, s1 = 0.f;
#pragma unroll
    for (int d = 0; d < 16; ++d) {
      s0 = fmaf(ea[d], M[d][2 * m], s0);
      s1 = fmaf(ea[d], M[d][2 * m + 1], s1);
    }
    pk[m] = (unsigned)f2bf(s0) | ((unsigned)f2bf(s1) << 16);
  }
  *(uint4*)(aedgeb + (size_t)e * 4) = make_uint4(pk[0], pk[1], pk[2], pk[3]);
  int sv = src[e], dv = dst[e];
  int pos = atomicAdd(&cursor[dv], 1);
  pair[pos] = make_int2(e, sv);
}

// ---------------- K8: fused alpha-recompute + softmax + aggregation + LN ----------
// one wave per node. Two half-wave teams each own alternate edges; lane owns
// 4 cols (c0 = 4*tl); head h = tl>>2. Teams combined via shfl_xor(.,32).
__global__ __launch_bounds__(512) void k_megaagg(
    const int* __restrict__ offsets, const int2* __restrict__ pair,
    const unsigned short* __restrict__ aedgeb, const unsigned short* __restrict__ a_srcb,
    const unsigned short* __restrict__ a_dstb, const unsigned* __restrict__ xb,
    const float* __restrict__ bias, const float* __restrict__ g,
    const float* __restrict__ b, float* __restrict__ node_out,
    float* __restrict__ inv_arr) {
  int w = threadIdx.x >> 6, l = threadIdx.x & 63;
  int n = blockIdx.x * 8 + w;
  if (n >= NN) return;
  int s = offsets[n], e = offsets[n + 1];
  int team = l >> 5, tl = l & 31;
  int h = tl >> 2;
  float ad = us_bf(a_dstb[(size_t)n * 8 + h]);  // wave-row uniform per head
  float den0 = 0.f, den1 = 0.f;
  float acc0[4] = {0.f, 0.f, 0.f, 0.f};
  float acc1[4] = {0.f, 0.f, 0.f, 0.f};
  int i = s + team;
  for (; i + 2 < e; i += 4) {
    int2 pA = pair[i], pB = pair[i + 2];
    float aeA = us_bf(aedgeb[(size_t)pA.x * 8 + h]);
    float aeB = us_bf(aedgeb[(size_t)pB.x * 8 + h]);
    float asA = us_bf(a_srcb[(size_t)pA.y * 8 + h]);
    float asB = us_bf(a_srcb[(size_t)pB.y * 8 + h]);
    uint2 xA = *(const uint2*)(xb + (size_t)pA.y * 64 + 2 * tl);
    uint2 xB = *(const uint2*)(xb + (size_t)pB.y * 64 + 2 * tl);
    float eA = __expf(lrelu02(asA + ad + aeA));
    float eB = __expf(lrelu02(asB + ad + aeB));
    den0 += eA; den1 += eB;
    acc0[0] = fmaf(eA, bf_lo(xA.x), acc0[0]);
    acc0[1] = fmaf(eA, bf_hi(xA.x), acc0[1]);
    acc0[2] = fmaf(eA, bf_lo(xA.y), acc0[2]);
    acc0[3] = fmaf(eA, bf_hi(xA.y), acc0[3]);
    acc1[0] = fmaf(eB, bf_lo(xB.x), acc1[0]);
    acc1[1] = fmaf(eB, bf_hi(xB.x), acc1[1]);
    acc1[2] = fmaf(eB, bf_lo(xB.y), acc1[2]);
    acc1[3] = fmaf(eB, bf_hi(xB.y), acc1[3]);
  }
  if (i < e) {
    int2 pA = pair[i];
    float aeA = us_bf(aedgeb[(size_t)pA.x * 8 + h]);
    float asA = us_bf(a_srcb[(size_t)pA.y * 8 + h]);
    uint2 xA = *(const uint2*)(xb + (size_t)pA.y * 64 + 2 * tl);
    float eA = __expf(lrelu02(asA + ad + aeA));
    den0 += eA;
    acc0[0] = fmaf(eA, bf_lo(xA.x), acc0[0]);
    acc0[1] = fmaf(eA, bf_hi(xA.x), acc0[1]);
    acc0[2] = fmaf(eA, bf_lo(xA.y), acc0[2]);
    acc0[3] = fmaf(eA, bf_hi(xA.y), acc0[3]);
  }
  float den = den0 + den1;
  den += __shfl_xor(den, 32);
  float acc[4];
#pragma unroll
  for (int j = 0; j < 4; ++j) {
    float v = acc0[j] + acc1[j];
    acc[j] = v + __shfl_xor(v, 32);
  }
  float inv = 1.f / (den + 1e-16f);
  if (team == 0 && (tl & 3) == 0) inv_arr[(size_t)n * 8 + h] = inv;
  int c0 = tl * 4;
  float4 bv = *(const float4*)(bias + c0);
#pragma unroll
  for (int j = 0; j < 4; ++j) acc[j] = acc[j] * inv;
  acc[0] += bv.x; acc[1] += bv.y; acc[2] += bv.z; acc[3] += bv.w;
  float sum = (acc[0] + acc[1]) + (acc[2] + acc[3]);
#pragma unroll
  for (int off = 1; off < 64; off <<= 1) sum += __shfl_xor(sum, off);
  float mu = sum * (1.f / 256.f);  // cols duplicated across teams
  float d0 = acc[0] - mu, d1 = acc[1] - mu, d2 = acc[2] - mu, d3 = acc[3] - mu;
  float ss = (d0 * d0 + d1 * d1) + (d2 * d2 + d3 * d3);
#pragma unroll
  for (int off = 1; off < 64; off <<= 1) ss += __shfl_xor(ss, off);
  float r = rsqrtf(ss * (1.f / 256.f) + LN_EPS);
  if (team == 0) {
    float4 gv = *(const float4*)(g + c0);
    float4 bbv = *(const float4*)(b + c0);
    float y0 = d0 * r * gv.x + bbv.x;
    float y1 = d1 * r * gv.y + bbv.y;
    float y2 = d2 * r * gv.z + bbv.z;
    float y3 = d3 * r * gv.w + bbv.w;
    y0 = y0 >= 0.f ? y0 : 0.01f * y0;
    y1 = y1 >= 0.f ? y1 : 0.01f * y1;
    y2 = y2 >= 0.f ? y2 : 0.01f * y2;
    y3 = y3 >= 0.f ? y3 : 0.01f * y3;
    *(float4*)(node_out + (size_t)n * 128 + c0) = make_float4(y0, y1, y2, y3);
  }
}

// ---------------- K9: edge out — recompute alpha, LN + linear + relu -------------
__global__ __launch_bounds__(256) void k_edgeout(
    const unsigned short* __restrict__ aedgeb, const unsigned short* __restrict__ a_srcb,
    const unsigned short* __restrict__ a_dstb, const int* __restrict__ src,
    const int* __restrict__ dst, const float* __restrict__ inv_arr,
    const float* __restrict__ g, const float* __restrict__ b,
    const float* __restrict__ ew, const float* __restrict__ eb,
    float* __restrict__ edge_out) {
  int i = blockIdx.x * 256 + threadIdx.x;
  if (i >= EE) return;
  int sv = src[i], dv = dst[i];
  uint4 ae4 = *(const uint4*)(aedgeb + (size_t)i * 8);
  uint4 as4 = *(const uint4*)(a_srcb + (size_t)sv * 8);
  uint4 ad4 = *(const uint4*)(a_dstb + (size_t)dv * 8);
  const float4* iv4 = (const float4*)(inv_arr + (size_t)dv * 8);
  float4 i0 = iv4[0], i1 = iv4[1];
  float iv[8] = {i0.x, i0.y, i0.z, i0.w, i1.x, i1.y, i1.z, i1.w};
  unsigned aeu[4] = {ae4.x, ae4.y, ae4.z, ae4.w};
  unsigned asu[4] = {as4.x, as4.y, as4.z, as4.w};
  unsigned adu[4] = {ad4.x, ad4.y, ad4.z, ad4.w};
  float p[8];
#pragma unroll
  for (int m = 0; m < 4; ++m) {
    float a0 = lrelu02(bf_lo(asu[m]) + bf_lo(adu[m]) + bf_lo(aeu[m]));
    float a1 = lrelu02(bf_hi(asu[m]) + bf_hi(adu[m]) + bf_hi(aeu[m]));
    p[2 * m] = __expf(a0) * iv[2 * m];
    p[2 * m + 1] = __expf(a1) * iv[2 * m + 1];
  }
  float mu = 0.f;
#pragma unroll
  for (int h = 0; h < 8; ++h) mu += p[h];
  mu *= 0.125f;
  float var = 0.f;
#pragma unroll
  for (int h = 0; h < 8; ++h) { float d = p[h] - mu; var += d * d; }
  var *= 0.125f;
  float r = rsqrtf(var + LN_EPS);
  float o = eb[0];
#pragma unroll
  for (int h = 0; h < 8; ++h)
    o += ((p[h] - mu) * r * g[h] + b[h]) * ew[h];
  edge_out[i] = fmaxf(o, 0.f);
}

extern "C" void kernel_launch(void* const* d_in, const int* in_sizes, int n_in,
                              void* d_out, int out_size, void* d_ws, size_t ws_size,
                              hipStream_t stream) {
  const void* edge_index = d_in[0];
  const float* point_attr = (const float*)d_in[1];
  const float* edge_attr = (const float*)d_in[2];
  const float* W = (const float*)d_in[3];
  const float* att_src = (const float*)d_in[4];
  const float* att_dst = (const float*)d_in[5];
  const float* W_edge = (const float*)d_in[6];
  const float* att_edge = (const float*)d_in[7];
  const float* bias = (const float*)d_in[8];
  const float* ln_node_g = (const float*)d_in[9];
  const float* ln_node_b = (const float*)d_in[10];
  const float* ln_edge_g = (const float*)d_in[11];
  const float* ln_edge_b = (const float*)d_in[12];
  const float* edge_w = (const float*)d_in[13];
  const float* edge_b = (const float*)d_in[14];

  char* wsb = (char*)d_ws;
  size_t o = 0;
  auto take = [&](size_t bytes) -> void* {
    void* p = wsb + o;
    o += (bytes + 255) & ~(size_t)255;
    return p;
  };
  int* flag = (int*)take(4);
  int* idx32 = (int*)take((size_t)2 * EE * 4);
  unsigned* xb = (unsigned*)take((size_t)NN * 128 * 2);
  unsigned short* a_srcb = (unsigned short*)take((size_t)NN * 8 * 2);
  unsigned short* a_dstb = (unsigned short*)take((size_t)NN * 8 * 2);
  int* counts = (int*)take((size_t)NN * 4);
  int* offsets = (int*)take((size_t)(NN + 1) * 4);
  int* cursor = (int*)take((size_t)NN * 4);
  int* partials = (int*)take(512 * 4);
  int2* pair = (int2*)take((size_t)EE * 8);
  unsigned* aedgeb = (unsigned*)take((size_t)EE * 8 * 2);
  float* inv_arr = (float*)take((size_t)NN * 8 * 4);

  const int* srcp = idx32;
  const int* dstp = idx32 + EE;
  float* node_out = (float*)d_out;
  float* edge_out = node_out + (size_t)NN * 128;

  int nb_scan = (NN + 255) / 256;  // 391

  hipMemsetAsync(counts, 0, (size_t)NN * 4, stream);

  k_detect<<<1, 64, 0, stream>>>(edge_index, flag);
  k_convert_hist<<<(2 * EE + 255) / 256, 256, 0, stream>>>(edge_index, flag, idx32, counts);
  k_gemm_node<<<(NN + 63) / 64, 512, 0, stream>>>(point_attr, W, att_src, att_dst,
                                                  xb, a_srcb, a_dstb, NN);
  k_blocksum<<<nb_scan, 256, 0, stream>>>(counts, partials, NN);
  k_scanpartials<<<1, 512, 0, stream>>>(partials, nb_scan);
  k_scanfinal<<<nb_scan, 256, 0, stream>>>(counts, partials, offsets, cursor, NN);
  k_edgeprep<<<(EE + 255) / 256, 256, 0, stream>>>(edge_attr, W_edge, att_edge, srcp,
                                                   dstp, cursor, pair, aedgeb);
  k_megaagg<<<(NN + 7) / 8, 512, 0, stream>>>(offsets, pair,
                                              (const unsigned short*)aedgeb, a_srcb,
                                              a_dstb, xb, bias, ln_node_g, ln_node_b,
                                              node_out, inv_arr);
  k_edgeout<<<(EE + 255) / 256, 256, 0, stream>>>((const unsigned short*)aedgeb, a_srcb,
                                                  a_dstb, srcp, dstp, inv_arr,
                                                  ln_edge_g, ln_edge_b, edge_w, edge_b,
                                                  edge_out);
}

// Round 5
// 383.558 us; speedup vs baseline: 1.0201x; 1.0201x over previous
//
#include <hip/hip_runtime.h>
#include <hip/hip_bf16.h>

#define NN 100000
#define EE 1600000
#define LN_EPS 1e-5f

typedef unsigned short ushort16;

__device__ __forceinline__ float bf_lo(unsigned u) {
  union { unsigned i; float f; } c; c.i = u << 16; return c.f;
}
__device__ __forceinline__ float bf_hi(unsigned u) {
  union { unsigned i; float f; } c; c.i = u & 0xffff0000u; return c.f;
}
__device__ __forceinline__ float us_bf(unsigned short u) {
  union { unsigned i; float f; } c; c.i = ((unsigned)u) << 16; return c.f;
}
__device__ __forceinline__ unsigned short f2bf(float f) {
  union { float f; unsigned i; } c; c.f = f;
  unsigned b = c.i + 0x7fffu + ((c.i >> 16) & 1u);
  return (unsigned short)(b >> 16);
}
__device__ __forceinline__ float lrelu02(float v) { return v >= 0.f ? v : 0.2f * v; }

// ---------------- K0: detect int64 vs int32 edge_index ----------------
__global__ void k_detect(const void* __restrict__ ei, int* __restrict__ flag) {
  if (threadIdx.x == 0 && blockIdx.x == 0) {
    const unsigned long long* p = (const unsigned long long*)ei;
    int ok = 1;
    for (int i = 0; i < 256; ++i)
      if (p[i] >= (unsigned long long)NN) { ok = 0; break; }
    *flag = ok;  // 1 => int64, 0 => int32
  }
}

// ---------------- K1: normalize edge_index to int32 + dst histogram (x2 vec) -----
__global__ __launch_bounds__(256) void k_convert_hist(const void* __restrict__ ei,
                                                      const int* __restrict__ flag,
                                                      int* __restrict__ idx32,
                                                      int* __restrict__ counts) {
  int gid = blockIdx.x * 256 + threadIdx.x;
  if (gid >= EE) return;  // handles elements 2*gid, 2*gid+1 of [0, 2*EE)
  int i0 = gid * 2;
  int v0, v1;
  if (*flag) {
    longlong2 lv = *(const longlong2*)((const long long*)ei + i0);
    v0 = (int)lv.x; v1 = (int)lv.y;
  } else {
    int2 iv = *(const int2*)((const int*)ei + i0);
    v0 = iv.x; v1 = iv.y;
  }
  *(int2*)(idx32 + i0) = make_int2(v0, v1);
  if (i0 >= EE) {
    atomicAdd(&counts[v0], 1);
    atomicAdd(&counts[v1], 1);
  }
}

// ---------------- K2: x = P@W (bf16 out), a_src/a_dst (bf16 out) ----------------
__global__ __launch_bounds__(512) void k_gemm_node(
    const float* __restrict__ P, const float* __restrict__ W,
    const float* __restrict__ attS, const float* __restrict__ attD,
    unsigned* __restrict__ xb, unsigned short* __restrict__ a_srcb,
    unsigned short* __restrict__ a_dstb, int nrows) {
  __shared__ float Rl[32 * 66];
  int t = threadIdx.x;
  int w = __builtin_amdgcn_readfirstlane(t >> 6);
  int l = t & 63;
  int rb = blockIdx.x * 64;
  int cb = w * 16;
  float acc[16];
#pragma unroll
  for (int j = 0; j < 16; ++j) acc[j] = 0.f;

  for (int kc = 0; kc < 4; ++kc) {
    __syncthreads();
    {
      int row = t >> 3;
      int k0 = (t & 7) * 4;
      int grow = rb + row;
      float4 v = make_float4(0.f, 0.f, 0.f, 0.f);
      if (grow < nrows)
        v = *(const float4*)(P + (size_t)grow * 128 + kc * 32 + k0);
      Rl[(k0 + 0) * 66 + row] = v.x;
      Rl[(k0 + 1) * 66 + row] = v.y;
      Rl[(k0 + 2) * 66 + row] = v.z;
      Rl[(k0 + 3) * 66 + row] = v.w;
    }
    __syncthreads();
    const float* Wp = W + (size_t)(kc * 32) * 128 + cb;
#pragma unroll 8
    for (int k = 0; k < 32; ++k) {
      float rv = Rl[k * 66 + l];
#pragma unroll
      for (int j = 0; j < 16; ++j) acc[j] = fmaf(rv, Wp[k * 128 + j], acc[j]);
    }
  }
  int row = rb + l;
  if (row < nrows) {
    float sa = 0.f, sd = 0.f;
#pragma unroll
    for (int j = 0; j < 16; ++j) {
      sa = fmaf(acc[j], attS[cb + j], sa);
      sd = fmaf(acc[j], attD[cb + j], sd);
    }
    a_srcb[(size_t)row * 8 + w] = f2bf(sa);
    a_dstb[(size_t)row * 8 + w] = f2bf(sd);
    unsigned pk[8];
#pragma unroll
    for (int m = 0; m < 8; ++m)
      pk[m] = (unsigned)f2bf(acc[2 * m]) | ((unsigned)f2bf(acc[2 * m + 1]) << 16);
    unsigned* xo = xb + (size_t)row * 64 + cb / 2;
    *(uint4*)(xo) = make_uint4(pk[0], pk[1], pk[2], pk[3]);
    *(uint4*)(xo + 4) = make_uint4(pk[4], pk[5], pk[6], pk[7]);
  }
}

// ---------------- K4: per-block sums ----------------
__global__ __launch_bounds__(256) void k_blocksum(const int* __restrict__ counts,
                                                  int* __restrict__ partials, int n) {
  __shared__ int sm[256];
  int t = threadIdx.x;
  int gid = blockIdx.x * 256 + t;
  sm[t] = gid < n ? counts[gid] : 0;
  __syncthreads();
  for (int s = 128; s > 0; s >>= 1) {
    if (t < s) sm[t] += sm[t + s];
    __syncthreads();
  }
  if (t == 0) partials[blockIdx.x] = sm[0];
}

// ---------------- K5: exclusive scan of partials ----------------
__global__ __launch_bounds__(512) void k_scanpartials(int* __restrict__ partials, int nb) {
  __shared__ int sm[512];
  int t = threadIdx.x;
  int v = t < nb ? partials[t] : 0;
  sm[t] = v;
  __syncthreads();
  for (int off = 1; off < 512; off <<= 1) {
    int u = (t >= off) ? sm[t - off] : 0;
    __syncthreads();
    sm[t] += u;
    __syncthreads();
  }
  if (t < nb) partials[t] = sm[t] - v;
}

// ---------------- K6: final exclusive scan -> offsets, cursor ----------------
__global__ __launch_bounds__(256) void k_scanfinal(const int* __restrict__ counts,
                                                   const int* __restrict__ partials,
                                                   int* __restrict__ offsets,
                                                   int* __restrict__ cursor, int n) {
  __shared__ int sm[256];
  int t = threadIdx.x;
  int gid = blockIdx.x * 256 + t;
  int v = gid < n ? counts[gid] : 0;
  sm[t] = v;
  __syncthreads();
  for (int off = 1; off < 256; off <<= 1) {
    int u = (t >= off) ? sm[t - off] : 0;
    __syncthreads();
    sm[t] += u;
    __syncthreads();
  }
  int excl = partials[blockIdx.x] + sm[t] - v;
  if (gid < n) {
    offsets[gid] = excl;
    cursor[gid] = excl;
  }
  if (gid == n - 1) offsets[n] = excl + v;
}

// ---------------- K7: a_edge (bf16, sequential) + CSR index scatter ----------------
__global__ __launch_bounds__(256) void k_edgeprep(
    const float* __restrict__ EA, const float* __restrict__ Wedge,
    const float* __restrict__ attE, const int* __restrict__ src,
    const int* __restrict__ dst, int* __restrict__ cursor,
    int2* __restrict__ pair, unsigned* __restrict__ aedgeb) {
  __shared__ float M[16][8];
  int t = threadIdx.x;
  if (t < 128) {
    int d = t >> 3, h = t & 7;
    float s = 0.f;
#pragma unroll
    for (int c = 0; c < 16; ++c)
      s = fmaf(Wedge[d * 128 + h * 16 + c], attE[h * 16 + c], s);
    M[d][h] = s;
  }
  __syncthreads();
  int e = blockIdx.x * 256 + t;
  if (e >= EE) return;
  float ea[16];
  const float4* ea4 = (const float4*)(EA + (size_t)e * 16);
#pragma unroll
  for (int i = 0; i < 4; ++i) {
    float4 v = ea4[i];
    ea[i * 4] = v.x; ea[i * 4 + 1] = v.y; ea[i * 4 + 2] = v.z; ea[i * 4 + 3] = v.w;
  }
  unsigned pk[4];
#pragma unroll
  for (int m = 0; m < 4; ++m) {
    float s0 = 0.f, s1 = 0.f;
#pragma unroll
    for (int d = 0; d < 16; ++d) {
      s0 = fmaf(ea[d], M[d][2 * m], s0);
      s1 = fmaf(ea[d], M[d][2 * m + 1], s1);
    }
    pk[m] = (unsigned)f2bf(s0) | ((unsigned)f2bf(s1) << 16);
  }
  *(uint4*)(aedgeb + (size_t)e * 4) = make_uint4(pk[0], pk[1], pk[2], pk[3]);
  int sv = src[e], dv = dst[e];
  int pos = atomicAdd(&cursor[dv], 1);
  pair[pos] = make_int2(e, sv);
}

// ---------------- K8: fused alpha-recompute + softmax + aggregation + LN ----------
// one wave per node. Four 16-lane quarter-teams own interleaved edge sub-streams;
// lane owns 8 cols (c0 = 8*ql) via one uint4 load; head h = ql>>1.
__global__ __launch_bounds__(512) void k_megaagg(
    const int* __restrict__ offsets, const int2* __restrict__ pair,
    const unsigned short* __restrict__ aedgeb, const unsigned short* __restrict__ a_srcb,
    const unsigned short* __restrict__ a_dstb, const unsigned* __restrict__ xb,
    const float* __restrict__ bias, const float* __restrict__ g,
    const float* __restrict__ b, float* __restrict__ node_out,
    float* __restrict__ inv_arr) {
  int w = threadIdx.x >> 6, l = threadIdx.x & 63;
  int n = blockIdx.x * 8 + w;
  if (n >= NN) return;
  int s = offsets[n], e = offsets[n + 1];
  int qt = l >> 4, ql = l & 15;
  int h = ql >> 1;
  float ad = us_bf(a_dstb[(unsigned)n * 8 + h]);
  float dn0 = 0.f, dn1 = 0.f;
  float acc[8] = {0.f, 0.f, 0.f, 0.f, 0.f, 0.f, 0.f, 0.f};
  int i = s + qt;
  for (; i + 4 < e; i += 8) {
    int2 pA = pair[i];
    int2 pB = pair[i + 4];
    float aeA = us_bf(aedgeb[(unsigned)pA.x * 8 + h]);
    float asA = us_bf(a_srcb[(unsigned)pA.y * 8 + h]);
    uint4 xA = *(const uint4*)(xb + (unsigned)pA.y * 64 + ql * 4);
    float aeB = us_bf(aedgeb[(unsigned)pB.x * 8 + h]);
    float asB = us_bf(a_srcb[(unsigned)pB.y * 8 + h]);
    uint4 xB = *(const uint4*)(xb + (unsigned)pB.y * 64 + ql * 4);
    float eA = __expf(lrelu02(asA + ad + aeA));
    float eB = __expf(lrelu02(asB + ad + aeB));
    dn0 += eA; dn1 += eB;
    acc[0] = fmaf(eA, bf_lo(xA.x), acc[0]);
    acc[1] = fmaf(eA, bf_hi(xA.x), acc[1]);
    acc[2] = fmaf(eA, bf_lo(xA.y), acc[2]);
    acc[3] = fmaf(eA, bf_hi(xA.y), acc[3]);
    acc[4] = fmaf(eA, bf_lo(xA.z), acc[4]);
    acc[5] = fmaf(eA, bf_hi(xA.z), acc[5]);
    acc[6] = fmaf(eA, bf_lo(xA.w), acc[6]);
    acc[7] = fmaf(eA, bf_hi(xA.w), acc[7]);
    acc[0] = fmaf(eB, bf_lo(xB.x), acc[0]);
    acc[1] = fmaf(eB, bf_hi(xB.x), acc[1]);
    acc[2] = fmaf(eB, bf_lo(xB.y), acc[2]);
    acc[3] = fmaf(eB, bf_hi(xB.y), acc[3]);
    acc[4] = fmaf(eB, bf_lo(xB.z), acc[4]);
    acc[5] = fmaf(eB, bf_hi(xB.z), acc[5]);
    acc[6] = fmaf(eB, bf_lo(xB.w), acc[6]);
    acc[7] = fmaf(eB, bf_hi(xB.w), acc[7]);
  }
  if (i < e) {
    int2 pA = pair[i];
    float aeA = us_bf(aedgeb[(unsigned)pA.x * 8 + h]);
    float asA = us_bf(a_srcb[(unsigned)pA.y * 8 + h]);
    uint4 xA = *(const uint4*)(xb + (unsigned)pA.y * 64 + ql * 4);
    float eA = __expf(lrelu02(asA + ad + aeA));
    dn0 += eA;
    acc[0] = fmaf(eA, bf_lo(xA.x), acc[0]);
    acc[1] = fmaf(eA, bf_hi(xA.x), acc[1]);
    acc[2] = fmaf(eA, bf_lo(xA.y), acc[2]);
    acc[3] = fmaf(eA, bf_hi(xA.y), acc[3]);
    acc[4] = fmaf(eA, bf_lo(xA.z), acc[4]);
    acc[5] = fmaf(eA, bf_hi(xA.z), acc[5]);
    acc[6] = fmaf(eA, bf_lo(xA.w), acc[6]);
    acc[7] = fmaf(eA, bf_hi(xA.w), acc[7]);
  }
  float den = dn0 + dn1;
  den += __shfl_xor(den, 16);
  den += __shfl_xor(den, 32);
#pragma unroll
  for (int j = 0; j < 8; ++j) {
    acc[j] += __shfl_xor(acc[j], 16);
    acc[j] += __shfl_xor(acc[j], 32);
  }
  float inv = 1.f / (den + 1e-16f);
  if (qt == 0 && (ql & 1) == 0) inv_arr[(unsigned)n * 8 + h] = inv;
  int c0 = ql * 8;
  float4 bv0 = *(const float4*)(bias + c0);
  float4 bv1 = *(const float4*)(bias + c0 + 4);
  acc[0] = acc[0] * inv + bv0.x;
  acc[1] = acc[1] * inv + bv0.y;
  acc[2] = acc[2] * inv + bv0.z;
  acc[3] = acc[3] * inv + bv0.w;
  acc[4] = acc[4] * inv + bv1.x;
  acc[5] = acc[5] * inv + bv1.y;
  acc[6] = acc[6] * inv + bv1.z;
  acc[7] = acc[7] * inv + bv1.w;
  float sum = ((acc[0] + acc[1]) + (acc[2] + acc[3])) +
              ((acc[4] + acc[5]) + (acc[6] + acc[7]));
#pragma unroll
  for (int off = 1; off < 64; off <<= 1) sum += __shfl_xor(sum, off);
  float mu = sum * (1.f / 512.f);  // cols duplicated across 4 quarter-teams
  float d[8], ss = 0.f;
#pragma unroll
  for (int j = 0; j < 8; ++j) { d[j] = acc[j] - mu; ss += d[j] * d[j]; }
#pragma unroll
  for (int off = 1; off < 64; off <<= 1) ss += __shfl_xor(ss, off);
  float r = rsqrtf(ss * (1.f / 512.f) + LN_EPS);
  if (qt == 0) {
    float4 gv0 = *(const float4*)(g + c0);
    float4 gv1 = *(const float4*)(g + c0 + 4);
    float4 bb0 = *(const float4*)(b + c0);
    float4 bb1 = *(const float4*)(b + c0 + 4);
    float y[8];
    y[0] = d[0] * r * gv0.x + bb0.x;
    y[1] = d[1] * r * gv0.y + bb0.y;
    y[2] = d[2] * r * gv0.z + bb0.z;
    y[3] = d[3] * r * gv0.w + bb0.w;
    y[4] = d[4] * r * gv1.x + bb1.x;
    y[5] = d[5] * r * gv1.y + bb1.y;
    y[6] = d[6] * r * gv1.z + bb1.z;
    y[7] = d[7] * r * gv1.w + bb1.w;
#pragma unroll
    for (int j = 0; j < 8; ++j) y[j] = y[j] >= 0.f ? y[j] : 0.01f * y[j];
    float* no = node_out + (size_t)n * 128 + c0;
    *(float4*)(no) = make_float4(y[0], y[1], y[2], y[3]);
    *(float4*)(no + 4) = make_float4(y[4], y[5], y[6], y[7]);
  }
}

// ---------------- K9: edge out — recompute alpha, LN + linear + relu (x2 unroll) --
__global__ __launch_bounds__(256) void k_edgeout(
    const unsigned short* __restrict__ aedgeb, const unsigned short* __restrict__ a_srcb,
    const unsigned short* __restrict__ a_dstb, const int* __restrict__ src,
    const int* __restrict__ dst, const float* __restrict__ inv_arr,
    const float* __restrict__ g, const float* __restrict__ b,
    const float* __restrict__ ew, const float* __restrict__ eb,
    float* __restrict__ edge_out) {
  int gid = blockIdx.x * 256 + threadIdx.x;
  if (gid * 2 >= EE) return;
  int i0 = gid * 2;
  float gl[8], bl[8], wl[8];
#pragma unroll
  for (int h = 0; h < 8; ++h) { gl[h] = g[h]; bl[h] = b[h]; wl[h] = ew[h]; }
  float ebv = eb[0];
  int2 svs = *(const int2*)(src + i0);
  int2 dvs = *(const int2*)(dst + i0);
  float out2[2];
#pragma unroll
  for (int u = 0; u < 2; ++u) {
    int i = i0 + u;
    int sv = (u == 0) ? svs.x : svs.y;
    int dv = (u == 0) ? dvs.x : dvs.y;
    uint4 ae4 = *(const uint4*)(aedgeb + (unsigned)i * 8);
    uint4 as4 = *(const uint4*)(a_srcb + (unsigned)sv * 8);
    uint4 ad4 = *(const uint4*)(a_dstb + (unsigned)dv * 8);
    const float4* iv4 = (const float4*)(inv_arr + (unsigned)dv * 8);
    float4 iv0 = iv4[0], iv1 = iv4[1];
    float iv[8] = {iv0.x, iv0.y, iv0.z, iv0.w, iv1.x, iv1.y, iv1.z, iv1.w};
    unsigned aeu[4] = {ae4.x, ae4.y, ae4.z, ae4.w};
    unsigned asu[4] = {as4.x, as4.y, as4.z, as4.w};
    unsigned adu[4] = {ad4.x, ad4.y, ad4.z, ad4.w};
    float p[8];
#pragma unroll
    for (int m = 0; m < 4; ++m) {
      float a0 = lrelu02(bf_lo(asu[m]) + bf_lo(adu[m]) + bf_lo(aeu[m]));
      float a1 = lrelu02(bf_hi(asu[m]) + bf_hi(adu[m]) + bf_hi(aeu[m]));
      p[2 * m] = __expf(a0) * iv[2 * m];
      p[2 * m + 1] = __expf(a1) * iv[2 * m + 1];
    }
    float mu = 0.f;
#pragma unroll
    for (int h = 0; h < 8; ++h) mu += p[h];
    mu *= 0.125f;
    float var = 0.f;
#pragma unroll
    for (int h = 0; h < 8; ++h) { float dd = p[h] - mu; var += dd * dd; }
    var *= 0.125f;
    float r = rsqrtf(var + LN_EPS);
    float o = ebv;
#pragma unroll
    for (int h = 0; h < 8; ++h)
      o += ((p[h] - mu) * r * gl[h] + bl[h]) * wl[h];
    out2[u] = fmaxf(o, 0.f);
  }
  *(float2*)(edge_out + i0) = make_float2(out2[0], out2[1]);
}

extern "C" void kernel_launch(void* const* d_in, const int* in_sizes, int n_in,
                              void* d_out, int out_size, void* d_ws, size_t ws_size,
                              hipStream_t stream) {
  const void* edge_index = d_in[0];
  const float* point_attr = (const float*)d_in[1];
  const float* edge_attr = (const float*)d_in[2];
  const float* W = (const float*)d_in[3];
  const float* att_src = (const float*)d_in[4];
  const float* att_dst = (const float*)d_in[5];
  const float* W_edge = (const float*)d_in[6];
  const float* att_edge = (const float*)d_in[7];
  const float* bias = (const float*)d_in[8];
  const float* ln_node_g = (const float*)d_in[9];
  const float* ln_node_b = (const float*)d_in[10];
  const float* ln_edge_g = (const float*)d_in[11];
  const float* ln_edge_b = (const float*)d_in[12];
  const float* edge_w = (const float*)d_in[13];
  const float* edge_b = (const float*)d_in[14];

  char* wsb = (char*)d_ws;
  size_t o = 0;
  auto take = [&](size_t bytes) -> void* {
    void* p = wsb + o;
    o += (bytes + 255) & ~(size_t)255;
    return p;
  };
  int* flag = (int*)take(4);
  int* idx32 = (int*)take((size_t)2 * EE * 4);
  unsigned* xb = (unsigned*)take((size_t)NN * 128 * 2);
  unsigned short* a_srcb = (unsigned short*)take((size_t)NN * 8 * 2);
  unsigned short* a_dstb = (unsigned short*)take((size_t)NN * 8 * 2);
  int* counts = (int*)take((size_t)NN * 4);
  int* offsets = (int*)take((size_t)(NN + 1) * 4);
  int* cursor = (int*)take((size_t)NN * 4);
  int* partials = (int*)take(512 * 4);
  int2* pair = (int2*)take((size_t)EE * 8);
  unsigned* aedgeb = (unsigned*)take((size_t)EE * 8 * 2);
  float* inv_arr = (float*)take((size_t)NN * 8 * 4);

  const int* srcp = idx32;
  const int* dstp = idx32 + EE;
  float* node_out = (float*)d_out;
  float* edge_out = node_out + (size_t)NN * 128;

  int nb_scan = (NN + 255) / 256;  // 391

  hipMemsetAsync(counts, 0, (size_t)NN * 4, stream);

  k_detect<<<1, 64, 0, stream>>>(edge_index, flag);
  k_convert_hist<<<(EE + 255) / 256, 256, 0, stream>>>(edge_index, flag, idx32, counts);
  k_gemm_node<<<(NN + 63) / 64, 512, 0, stream>>>(point_attr, W, att_src, att_dst,
                                                  xb, a_srcb, a_dstb, NN);
  k_blocksum<<<nb_scan, 256, 0, stream>>>(counts, partials, NN);
  k_scanpartials<<<1, 512, 0, stream>>>(partials, nb_scan);
  k_scanfinal<<<nb_scan, 256, 0, stream>>>(counts, partials, offsets, cursor, NN);
  k_edgeprep<<<(EE + 255) / 256, 256, 0, stream>>>(edge_attr, W_edge, att_edge, srcp,
                                                   dstp, cursor, pair, aedgeb);
  k_megaagg<<<(NN + 7) / 8, 512, 0, stream>>>(offsets, pair,
                                              (const unsigned short*)aedgeb, a_srcb,
                                              a_dstb, xb, bias, ln_node_g, ln_node_b,
                                              node_out, inv_arr);
  k_edgeout<<<(EE / 2 + 255) / 256, 256, 0, stream>>>((const unsigned short*)aedgeb,
                                                      a_srcb, a_dstb, srcp, dstp,
                                                      inv_arr, ln_edge_g, ln_edge_b,
                                                      edge_w, edge_b, edge_out);
}

// Round 7
// 355.771 us; speedup vs baseline: 1.0998x; 1.0781x over previous
//
#include <hip/hip_runtime.h>
#include <hip/hip_bf16.h>

#define NN 100000
#define EE 1600000
#define LN_EPS 1e-5f

__device__ __forceinline__ float bf_lo(unsigned u) {
  union { unsigned i; float f; } c; c.i = u << 16; return c.f;
}
__device__ __forceinline__ float bf_hi(unsigned u) {
  union { unsigned i; float f; } c; c.i = u & 0xffff0000u; return c.f;
}
__device__ __forceinline__ float us_bf(unsigned short u) {
  union { unsigned i; float f; } c; c.i = ((unsigned)u) << 16; return c.f;
}
__device__ __forceinline__ unsigned short f2bf(float f) {
  union { float f; unsigned i; } c; c.f = f;
  unsigned b = c.i + 0x7fffu + ((c.i >> 16) & 1u);
  return (unsigned short)(b >> 16);
}
__device__ __forceinline__ float lrelu02(float v) { return v >= 0.f ? v : 0.2f * v; }

// ---------------- K0: detect int64 vs int32 edge_index ----------------
__global__ void k_detect(const void* __restrict__ ei, int* __restrict__ flag) {
  if (threadIdx.x == 0 && blockIdx.x == 0) {
    const unsigned long long* p = (const unsigned long long*)ei;
    int ok = 1;
    for (int i = 0; i < 256; ++i)
      if (p[i] >= (unsigned long long)NN) { ok = 0; break; }
    *flag = ok;  // 1 => int64, 0 => int32
  }
}

// ---------------- K1: normalize edge_index to int32 + dst histogram (x2 vec) -----
__global__ __launch_bounds__(256) void k_convert_hist(const void* __restrict__ ei,
                                                      const int* __restrict__ flag,
                                                      int* __restrict__ idx32,
                                                      int* __restrict__ counts) {
  int gid = blockIdx.x * 256 + threadIdx.x;
  if (gid >= EE) return;  // handles elements 2*gid, 2*gid+1 of [0, 2*EE)
  int i0 = gid * 2;
  int v0, v1;
  if (*flag) {
    longlong2 lv = *(const longlong2*)((const long long*)ei + i0);
    v0 = (int)lv.x; v1 = (int)lv.y;
  } else {
    int2 iv = *(const int2*)((const int*)ei + i0);
    v0 = iv.x; v1 = iv.y;
  }
  *(int2*)(idx32 + i0) = make_int2(v0, v1);
  if (i0 >= EE) {
    atomicAdd(&counts[v0], 1);
    atomicAdd(&counts[v1], 1);
  }
}

// ---------------- K2: x = P@W (bf16 out), a_src/a_dst (bf16 out) ----------------
__global__ __launch_bounds__(512) void k_gemm_node(
    const float* __restrict__ P, const float* __restrict__ W,
    const float* __restrict__ attS, const float* __restrict__ attD,
    unsigned* __restrict__ xb, unsigned short* __restrict__ a_srcb,
    unsigned short* __restrict__ a_dstb, int nrows) {
  __shared__ float Rl[32 * 66];
  int t = threadIdx.x;
  int w = __builtin_amdgcn_readfirstlane(t >> 6);
  int l = t & 63;
  int rb = blockIdx.x * 64;
  int cb = w * 16;
  float acc[16];
#pragma unroll
  for (int j = 0; j < 16; ++j) acc[j] = 0.f;

  for (int kc = 0; kc < 4; ++kc) {
    __syncthreads();
    {
      int row = t >> 3;
      int k0 = (t & 7) * 4;
      int grow = rb + row;
      float4 v = make_float4(0.f, 0.f, 0.f, 0.f);
      if (grow < nrows)
        v = *(const float4*)(P + (size_t)grow * 128 + kc * 32 + k0);
      Rl[(k0 + 0) * 66 + row] = v.x;
      Rl[(k0 + 1) * 66 + row] = v.y;
      Rl[(k0 + 2) * 66 + row] = v.z;
      Rl[(k0 + 3) * 66 + row] = v.w;
    }
    __syncthreads();
    const float* Wp = W + (size_t)(kc * 32) * 128 + cb;
#pragma unroll 8
    for (int k = 0; k < 32; ++k) {
      float rv = Rl[k * 66 + l];
#pragma unroll
      for (int j = 0; j < 16; ++j) acc[j] = fmaf(rv, Wp[k * 128 + j], acc[j]);
    }
  }
  int row = rb + l;
  if (row < nrows) {
    float sa = 0.f, sd = 0.f;
#pragma unroll
    for (int j = 0; j < 16; ++j) {
      sa = fmaf(acc[j], attS[cb + j], sa);
      sd = fmaf(acc[j], attD[cb + j], sd);
    }
    a_srcb[(size_t)row * 8 + w] = f2bf(sa);
    a_dstb[(size_t)row * 8 + w] = f2bf(sd);
    unsigned pk[8];
#pragma unroll
    for (int m = 0; m < 8; ++m)
      pk[m] = (unsigned)f2bf(acc[2 * m]) | ((unsigned)f2bf(acc[2 * m + 1]) << 16);
    unsigned* xo = xb + (size_t)row * 64 + cb / 2;
    *(uint4*)(xo) = make_uint4(pk[0], pk[1], pk[2], pk[3]);
    *(uint4*)(xo + 4) = make_uint4(pk[4], pk[5], pk[6], pk[7]);
  }
}

// ---------------- K4: per-block sums ----------------
__global__ __launch_bounds__(256) void k_blocksum(const int* __restrict__ counts,
                                                  int* __restrict__ partials, int n) {
  __shared__ int sm[256];
  int t = threadIdx.x;
  int gid = blockIdx.x * 256 + t;
  sm[t] = gid < n ? counts[gid] : 0;
  __syncthreads();
  for (int s = 128; s > 0; s >>= 1) {
    if (t < s) sm[t] += sm[t + s];
    __syncthreads();
  }
  if (t == 0) partials[blockIdx.x] = sm[0];
}

// ---------------- K5: exclusive scan of partials ----------------
__global__ __launch_bounds__(512) void k_scanpartials(int* __restrict__ partials, int nb) {
  __shared__ int sm[512];
  int t = threadIdx.x;
  int v = t < nb ? partials[t] : 0;
  sm[t] = v;
  __syncthreads();
  for (int off = 1; off < 512; off <<= 1) {
    int u = (t >= off) ? sm[t - off] : 0;
    __syncthreads();
    sm[t] += u;
    __syncthreads();
  }
  if (t < nb) partials[t] = sm[t] - v;
}

// ---------------- K6: final exclusive scan -> offsets, cursor ----------------
__global__ __launch_bounds__(256) void k_scanfinal(const int* __restrict__ counts,
                                                   const int* __restrict__ partials,
                                                   int* __restrict__ offsets,
                                                   int* __restrict__ cursor, int n) {
  __shared__ int sm[256];
  int t = threadIdx.x;
  int gid = blockIdx.x * 256 + t;
  int v = gid < n ? counts[gid] : 0;
  sm[t] = v;
  __syncthreads();
  for (int off = 1; off < 256; off <<= 1) {
    int u = (t >= off) ? sm[t - off] : 0;
    __syncthreads();
    sm[t] += u;
    __syncthreads();
  }
  int excl = partials[blockIdx.x] + sm[t] - v;
  if (gid < n) {
    offsets[gid] = excl;
    cursor[gid] = excl;
  }
  if (gid == n - 1) offsets[n] = excl + v;
}

// ---------------- K7: asum = a_src[sv]+a_edge -> orig-order (seq) + sorted 32B rec
__global__ __launch_bounds__(256) void k_edgeprep(
    const float* __restrict__ EA, const float* __restrict__ Wedge,
    const float* __restrict__ attE, const int* __restrict__ src,
    const int* __restrict__ dst, const unsigned short* __restrict__ a_srcb,
    int* __restrict__ cursor, unsigned* __restrict__ rec,
    unsigned* __restrict__ asumb) {
  __shared__ float M[16][8];
  int t = threadIdx.x;
  if (t < 128) {
    int d = t >> 3, h = t & 7;
    float s = 0.f;
#pragma unroll
    for (int c = 0; c < 16; ++c)
      s = fmaf(Wedge[d * 128 + h * 16 + c], attE[h * 16 + c], s);
    M[d][h] = s;
  }
  __syncthreads();
  int e = blockIdx.x * 256 + t;
  if (e >= EE) return;
  float ea[16];
  const float4* ea4 = (const float4*)(EA + (size_t)e * 16);
#pragma unroll
  for (int i = 0; i < 4; ++i) {
    float4 v = ea4[i];
    ea[i * 4] = v.x; ea[i * 4 + 1] = v.y; ea[i * 4 + 2] = v.z; ea[i * 4 + 3] = v.w;
  }
  int sv = src[e], dv = dst[e];
  uint4 as4 = *(const uint4*)(a_srcb + (unsigned)sv * 8);
  unsigned asu[4] = {as4.x, as4.y, as4.z, as4.w};
  unsigned pk[4];
#pragma unroll
  for (int m = 0; m < 4; ++m) {
    float s0 = 0.f, s1 = 0.f;
#pragma unroll
    for (int d = 0; d < 16; ++d) {
      s0 = fmaf(ea[d], M[d][2 * m], s0);
      s1 = fmaf(ea[d], M[d][2 * m + 1], s1);
    }
    s0 += bf_lo(asu[m]);
    s1 += bf_hi(asu[m]);
    pk[m] = (unsigned)f2bf(s0) | ((unsigned)f2bf(s1) << 16);
  }
  uint4 asum = make_uint4(pk[0], pk[1], pk[2], pk[3]);
  *(uint4*)(asumb + (size_t)e * 4) = asum;  // orig order, sequential (for edgeout)
  int pos = atomicAdd(&cursor[dv], 1);
  unsigned* rp = rec + (size_t)pos * 8;     // 32 B sector-aligned record
  *(uint4*)(rp) = asum;
  *(uint4*)(rp + 4) = make_uint4((unsigned)sv, (unsigned)e, 0u, 0u);
}

// ---------------- K8: fused alpha-recompute + softmax + aggregation + LN ----------
// one wave per node. Four 16-lane quarter-teams own interleaved edge sub-streams;
// lane owns 8 cols (c0 = 8*ql) via one uint4 load; head h = ql>>1.
// rec read is sequential; only xb is gathered (single dependent-load level).
__global__ __launch_bounds__(512) void k_megaagg(
    const int* __restrict__ offsets, const unsigned* __restrict__ rec,
    const unsigned short* __restrict__ a_dstb, const unsigned* __restrict__ xb,
    const float* __restrict__ bias, const float* __restrict__ g,
    const float* __restrict__ b, float* __restrict__ node_out,
    float* __restrict__ inv_arr) {
  int w = threadIdx.x >> 6, l = threadIdx.x & 63;
  int n = blockIdx.x * 8 + w;
  if (n >= NN) return;
  int s = offsets[n], e = offsets[n + 1];
  int qt = l >> 4, ql = l & 15;
  int h = ql >> 1;
  int hsel = (ql >> 1) & 1;  // head's half within its packed word: h&1
  int hw = ql >> 2;          // u32 word index of head pair: h>>1
  float ad = us_bf(a_dstb[(unsigned)n * 8 + h]);
  float dn0 = 0.f, dn1 = 0.f;
  float acc[8] = {0.f, 0.f, 0.f, 0.f, 0.f, 0.f, 0.f, 0.f};
  int i = s + qt;
  for (; i + 4 < e; i += 8) {
    unsigned auA = rec[(size_t)i * 8 + hw];
    int svA = (int)rec[(size_t)i * 8 + 4];
    unsigned auB = rec[(size_t)(i + 4) * 8 + hw];
    int svB = (int)rec[(size_t)(i + 4) * 8 + 4];
    uint4 xA = *(const uint4*)(xb + (unsigned)svA * 64 + ql * 4);
    uint4 xB = *(const uint4*)(xb + (unsigned)svB * 64 + ql * 4);
    float aA = hsel ? bf_hi(auA) : bf_lo(auA);
    float aB = hsel ? bf_hi(auB) : bf_lo(auB);
    float eA = __expf(lrelu02(aA + ad));
    float eB = __expf(lrelu02(aB + ad));
    dn0 += eA; dn1 += eB;
    acc[0] = fmaf(eA, bf_lo(xA.x), acc[0]);
    acc[1] = fmaf(eA, bf_hi(xA.x), acc[1]);
    acc[2] = fmaf(eA, bf_lo(xA.y), acc[2]);
    acc[3] = fmaf(eA, bf_hi(xA.y), acc[3]);
    acc[4] = fmaf(eA, bf_lo(xA.z), acc[4]);
    acc[5] = fmaf(eA, bf_hi(xA.z), acc[5]);
    acc[6] = fmaf(eA, bf_lo(xA.w), acc[6]);
    acc[7] = fmaf(eA, bf_hi(xA.w), acc[7]);
    acc[0] = fmaf(eB, bf_lo(xB.x), acc[0]);
    acc[1] = fmaf(eB, bf_hi(xB.x), acc[1]);
    acc[2] = fmaf(eB, bf_lo(xB.y), acc[2]);
    acc[3] = fmaf(eB, bf_hi(xB.y), acc[3]);
    acc[4] = fmaf(eB, bf_lo(xB.z), acc[4]);
    acc[5] = fmaf(eB, bf_hi(xB.z), acc[5]);
    acc[6] = fmaf(eB, bf_lo(xB.w), acc[6]);
    acc[7] = fmaf(eB, bf_hi(xB.w), acc[7]);
  }
  if (i < e) {
    unsigned auA = rec[(size_t)i * 8 + hw];
    int svA = (int)rec[(size_t)i * 8 + 4];
    uint4 xA = *(const uint4*)(xb + (unsigned)svA * 64 + ql * 4);
    float aA = hsel ? bf_hi(auA) : bf_lo(auA);
    float eA = __expf(lrelu02(aA + ad));
    dn0 += eA;
    acc[0] = fmaf(eA, bf_lo(xA.x), acc[0]);
    acc[1] = fmaf(eA, bf_hi(xA.x), acc[1]);
    acc[2] = fmaf(eA, bf_lo(xA.y), acc[2]);
    acc[3] = fmaf(eA, bf_hi(xA.y), acc[3]);
    acc[4] = fmaf(eA, bf_lo(xA.z), acc[4]);
    acc[5] = fmaf(eA, bf_hi(xA.z), acc[5]);
    acc[6] = fmaf(eA, bf_lo(xA.w), acc[6]);
    acc[7] = fmaf(eA, bf_hi(xA.w), acc[7]);
  }
  float den = dn0 + dn1;
  den += __shfl_xor(den, 16);
  den += __shfl_xor(den, 32);
#pragma unroll
  for (int j = 0; j < 8; ++j) {
    acc[j] += __shfl_xor(acc[j], 16);
    acc[j] += __shfl_xor(acc[j], 32);
  }
  float inv = 1.f / (den + 1e-16f);
  if (qt == 0 && (ql & 1) == 0) inv_arr[(unsigned)n * 8 + h] = inv;
  int c0 = ql * 8;
  float4 bv0 = *(const float4*)(bias + c0);
  float4 bv1 = *(const float4*)(bias + c0 + 4);
  acc[0] = acc[0] * inv + bv0.x;
  acc[1] = acc[1] * inv + bv0.y;
  acc[2] = acc[2] * inv + bv0.z;
  acc[3] = acc[3] * inv + bv0.w;
  acc[4] = acc[4] * inv + bv1.x;
  acc[5] = acc[5] * inv + bv1.y;
  acc[6] = acc[6] * inv + bv1.z;
  acc[7] = acc[7] * inv + bv1.w;
  float sum = ((acc[0] + acc[1]) + (acc[2] + acc[3])) +
              ((acc[4] + acc[5]) + (acc[6] + acc[7]));
#pragma unroll
  for (int off = 1; off < 64; off <<= 1) sum += __shfl_xor(sum, off);
  float mu = sum * (1.f / 512.f);  // cols duplicated across 4 quarter-teams
  float d[8], ss = 0.f;
#pragma unroll
  for (int j = 0; j < 8; ++j) { d[j] = acc[j] - mu; ss += d[j] * d[j]; }
#pragma unroll
  for (int off = 1; off < 64; off <<= 1) ss += __shfl_xor(ss, off);
  float r = rsqrtf(ss * (1.f / 512.f) + LN_EPS);
  if (qt == 0) {
    float4 gv0 = *(const float4*)(g + c0);
    float4 gv1 = *(const float4*)(g + c0 + 4);
    float4 bb0 = *(const float4*)(b + c0);
    float4 bb1 = *(const float4*)(b + c0 + 4);
    float y[8];
    y[0] = d[0] * r * gv0.x + bb0.x;
    y[1] = d[1] * r * gv0.y + bb0.y;
    y[2] = d[2] * r * gv0.z + bb0.z;
    y[3] = d[3] * r * gv0.w + bb0.w;
    y[4] = d[4] * r * gv1.x + bb1.x;
    y[5] = d[5] * r * gv1.y + bb1.y;
    y[6] = d[6] * r * gv1.z + bb1.z;
    y[7] = d[7] * r * gv1.w + bb1.w;
#pragma unroll
    for (int j = 0; j < 8; ++j) y[j] = y[j] >= 0.f ? y[j] : 0.01f * y[j];
    float* no = node_out + (size_t)n * 128 + c0;
    *(float4*)(no) = make_float4(y[0], y[1], y[2], y[3]);
    *(float4*)(no + 4) = make_float4(y[4], y[5], y[6], y[7]);
  }
}

// ---------------- K9: edge out — alpha = lrelu(asum + adst), LN + linear + relu ---
__global__ __launch_bounds__(256) void k_edgeout(
    const unsigned* __restrict__ asumb, const unsigned short* __restrict__ a_dstb,
    const int* __restrict__ dst, const float* __restrict__ inv_arr,
    const float* __restrict__ g, const float* __restrict__ b,
    const float* __restrict__ ew, const float* __restrict__ eb,
    float* __restrict__ edge_out) {
  int gid = blockIdx.x * 256 + threadIdx.x;
  if (gid * 2 >= EE) return;
  int i0 = gid * 2;
  float gl[8], bl[8], wl[8];
#pragma unroll
  for (int h = 0; h < 8; ++h) { gl[h] = g[h]; bl[h] = b[h]; wl[h] = ew[h]; }
  float ebv = eb[0];
  int2 dvs = *(const int2*)(dst + i0);
  float out2[2];
#pragma unroll
  for (int u = 0; u < 2; ++u) {
    int i = i0 + u;
    int dv = (u == 0) ? dvs.x : dvs.y;
    uint4 as4 = *(const uint4*)(asumb + (size_t)i * 4);
    uint4 ad4 = *(const uint4*)(a_dstb + (unsigned)dv * 8);
    const float4* iv4 = (const float4*)(inv_arr + (unsigned)dv * 8);
    float4 iv0 = iv4[0], iv1 = iv4[1];
    float iv[8] = {iv0.x, iv0.y, iv0.z, iv0.w, iv1.x, iv1.y, iv1.z, iv1.w};
    unsigned asu[4] = {as4.x, as4.y, as4.z, as4.w};
    unsigned adu[4] = {ad4.x, ad4.y, ad4.z, ad4.w};
    float p[8];
#pragma unroll
    for (int m = 0; m < 4; ++m) {
      float a0 = lrelu02(bf_lo(asu[m]) + bf_lo(adu[m]));
      float a1 = lrelu02(bf_hi(asu[m]) + bf_hi(adu[m]));
      p[2 * m] = __expf(a0) * iv[2 * m];
      p[2 * m + 1] = __expf(a1) * iv[2 * m + 1];
    }
    float mu = 0.f;
#pragma unroll
    for (int h = 0; h < 8; ++h) mu += p[h];
    mu *= 0.125f;
    float var = 0.f;
#pragma unroll
    for (int h = 0; h < 8; ++h) { float dd = p[h] - mu; var += dd * dd; }
    var *= 0.125f;
    float r = rsqrtf(var + LN_EPS);
    float o = ebv;
#pragma unroll
    for (int h = 0; h < 8; ++h)
      o += ((p[h] - mu) * r * gl[h] + bl[h]) * wl[h];
    out2[u] = fmaxf(o, 0.f);
  }
  *(float2*)(edge_out + i0) = make_float2(out2[0], out2[1]);
}

extern "C" void kernel_launch(void* const* d_in, const int* in_sizes, int n_in,
                              void* d_out, int out_size, void* d_ws, size_t ws_size,
                              hipStream_t stream) {
  const void* edge_index = d_in[0];
  const float* point_attr = (const float*)d_in[1];
  const float* edge_attr = (const float*)d_in[2];
  const float* W = (const float*)d_in[3];
  const float* att_src = (const float*)d_in[4];
  const float* att_dst = (const float*)d_in[5];
  const float* W_edge = (const float*)d_in[6];
  const float* att_edge = (const float*)d_in[7];
  const float* bias = (const float*)d_in[8];
  const float* ln_node_g = (const float*)d_in[9];
  const float* ln_node_b = (const float*)d_in[10];
  const float* ln_edge_g = (const float*)d_in[11];
  const float* ln_edge_b = (const float*)d_in[12];
  const float* edge_w = (const float*)d_in[13];
  const float* edge_b = (const float*)d_in[14];

  char* wsb = (char*)d_ws;
  size_t o = 0;
  auto take = [&](size_t bytes) -> void* {
    void* p = wsb + o;
    o += (bytes + 255) & ~(size_t)255;
    return p;
  };
  int* flag = (int*)take(4);
  int* idx32 = (int*)take((size_t)2 * EE * 4);
  unsigned* xb = (unsigned*)take((size_t)NN * 128 * 2);
  unsigned short* a_srcb = (unsigned short*)take((size_t)NN * 8 * 2);
  unsigned short* a_dstb = (unsigned short*)take((size_t)NN * 8 * 2);
  int* counts = (int*)take((size_t)NN * 4);
  int* offsets = (int*)take((size_t)(NN + 1) * 4);
  int* cursor = (int*)take((size_t)NN * 4);
  int* partials = (int*)take(512 * 4);
  unsigned* rec = (unsigned*)take((size_t)EE * 32);     // 32 B sorted records
  unsigned* asumb = (unsigned*)take((size_t)EE * 16);   // orig-order asum rows
  float* inv_arr = (float*)take((size_t)NN * 8 * 4);

  const int* srcp = idx32;
  const int* dstp = idx32 + EE;
  float* node_out = (float*)d_out;
  float* edge_out = node_out + (size_t)NN * 128;

  int nb_scan = (NN + 255) / 256;  // 391

  hipMemsetAsync(counts, 0, (size_t)NN * 4, stream);

  k_detect<<<1, 64, 0, stream>>>(edge_index, flag);
  k_convert_hist<<<(EE + 255) / 256, 256, 0, stream>>>(edge_index, flag, idx32, counts);
  k_gemm_node<<<(NN + 63) / 64, 512, 0, stream>>>(point_attr, W, att_src, att_dst,
                                                  xb, a_srcb, a_dstb, NN);
  k_blocksum<<<nb_scan, 256, 0, stream>>>(counts, partials, NN);
  k_scanpartials<<<1, 512, 0, stream>>>(partials, nb_scan);
  k_scanfinal<<<nb_scan, 256, 0, stream>>>(counts, partials, offsets, cursor, NN);
  k_edgeprep<<<(EE + 255) / 256, 256, 0, stream>>>(edge_attr, W_edge, att_edge, srcp,
                                                   dstp, a_srcb, cursor, rec, asumb);
  k_megaagg<<<(NN + 7) / 8, 512, 0, stream>>>(offsets, rec, a_dstb, xb, bias,
                                              ln_node_g, ln_node_b, node_out, inv_arr);
  k_edgeout<<<(EE / 2 + 255) / 256, 256, 0, stream>>>(asumb, a_dstb, dstp, inv_arr,
                                                      ln_edge_g, ln_edge_b, edge_w,
                                                      edge_b, edge_out);
}